// Round 1
// 1233.058 us; speedup vs baseline: 1.0365x; 1.0365x over previous
//
#include <hip/hip_runtime.h>
#include <cstdint>
#include <cmath>

#define S_LEN 4096
#define H_DIM 2304
#define NQH   8
#define NKVH  4
#define HDIM  256
#define INTER 9216
#define QKV_N 4096   // (NQ + 2*NKV) * HD
#define QH    2048   // NQ*HD
#define KVH   1024   // NKV*HD

typedef __attribute__((ext_vector_type(4))) float  f32x4;
typedef __attribute__((ext_vector_type(8))) __bf16 bf16x8;

__device__ __forceinline__ __bf16 f2bf(float f) {
  union { float f; unsigned u; } x; x.f = f;
  unsigned r = (x.u + 0x7fffu + ((x.u >> 16) & 1u)) >> 16;   // RNE
  union { unsigned short s; __bf16 b; } y; y.s = (unsigned short)r;
  return y.b;
}

// async global->LDS, 16B per lane. LDS dest must be wave-uniform base + lane*16.
__device__ __forceinline__ void g2l16(const void* g, void* l) {
  __builtin_amdgcn_global_load_lds(
      (__attribute__((address_space(1))) void*)(uintptr_t)g,
      (__attribute__((address_space(3))) void*)(uint32_t)(uintptr_t)l, 16, 0, 0);
}

__device__ __forceinline__ float block_sum(float v, float* sbuf) {
  #pragma unroll
  for (int o = 32; o > 0; o >>= 1) v += __shfl_xor(v, o);
  __syncthreads();
  if ((threadIdx.x & 63) == 0) sbuf[threadIdx.x >> 6] = v;
  __syncthreads();
  return sbuf[0] + sbuf[1] + sbuf[2] + sbuf[3];
}

// ---------------- weight conversion: fp32 [K][N] -> bf16 [N][K] (B^T) ---------
__global__ void conv_t_kernel(const float* __restrict__ src, __bf16* __restrict__ dst,
                              int srcStride, int dstStride) {
  __shared__ float t[32][33];
  int tx = threadIdx.x & 31, ty = threadIdx.x >> 5;
  int n0 = blockIdx.x * 32, k0 = blockIdx.y * 32;
  #pragma unroll
  for (int l = 0; l < 4; ++l) {
    int ky = ty + l * 8;
    t[tx][ky] = src[(long)(k0 + ky) * srcStride + n0 + tx];
  }
  __syncthreads();
  #pragma unroll
  for (int l = 0; l < 4; ++l) {
    int ny = ty + l * 8;
    dst[(long)(n0 + ny) * dstStride + k0 + tx] = f2bf(t[ny][tx]);
  }
}

// gate/up interleave permutation (derived for the 128-col tile epilogue pairing;
// the 256-col tile epilogue below re-derives the same map with wn in 0..3)
__device__ __forceinline__ int gu_map(int n) {
  int t = n >> 7, w = (n >> 6) & 1, j = (n >> 4) & 3, c = n & 15;
  int a = t * 64 + w * 32 + ((j >> 1) << 4) + c;
  return (j & 1) ? (INTER + a) : a;
}

__global__ void conv_gu_kernel(const float* __restrict__ src, __bf16* __restrict__ dst) {
  __shared__ float t[32][33];
  int tx = threadIdx.x & 31, ty = threadIdx.x >> 5;
  int n0 = blockIdx.x * 32, k0 = blockIdx.y * 32;
  int sc = gu_map(n0 + tx);
  #pragma unroll
  for (int l = 0; l < 4; ++l) {
    int ky = ty + l * 8;
    t[tx][ky] = src[(long)(k0 + ky) * (2 * INTER) + sc];
  }
  __syncthreads();
  #pragma unroll
  for (int l = 0; l < 4; ++l) {
    int ny = ty + l * 8;
    dst[(long)(n0 + ny) * H_DIM + k0 + tx] = f2bf(t[ny][tx]);
  }
}

// ---------------- rmsnorm kernels (H = 2304 = 9*256) --------------------------
__global__ void rms_in_kernel(const float* __restrict__ x, const float* __restrict__ w,
                              __bf16* __restrict__ out) {
  __shared__ float sbuf[4];
  int row = blockIdx.x, tid = threadIdx.x;
  const float* xr = x + (long)row * H_DIM;
  float v[9]; float ss = 0.f;
  #pragma unroll
  for (int i = 0; i < 9; ++i) { v[i] = xr[tid + i * 256]; ss += v[i] * v[i]; }
  ss = block_sum(ss, sbuf);
  float inv = rsqrtf(ss * (1.0f / H_DIM) + 1e-6f);
  #pragma unroll
  for (int i = 0; i < 9; ++i)
    out[(long)row * H_DIM + tid + i * 256] = f2bf(v[i] * inv * (1.f + w[tid + i * 256]));
}

__global__ void rms_post_attn_kernel(const float* __restrict__ P, const float* __restrict__ hidden,
                                     const float* __restrict__ w_post, const float* __restrict__ w_pre,
                                     float* __restrict__ resid, __bf16* __restrict__ x2) {
  __shared__ float sbuf[4];
  int row = blockIdx.x, tid = threadIdx.x;
  const float* pr = P + (long)row * H_DIM;
  const float* hr = hidden + (long)row * H_DIM;
  float pv[9]; float ss = 0.f;
  #pragma unroll
  for (int i = 0; i < 9; ++i) { pv[i] = pr[tid + i * 256]; ss += pv[i] * pv[i]; }
  ss = block_sum(ss, sbuf);
  float inv = rsqrtf(ss * (1.0f / H_DIM) + 1e-6f);
  float rv[9]; float ss2 = 0.f;
  #pragma unroll
  for (int i = 0; i < 9; ++i) {
    int c = tid + i * 256;
    float hn = pv[i] * inv * (1.f + w_post[c]);
    rv[i] = hn + hr[c];
    resid[(long)row * H_DIM + c] = rv[i];
    ss2 += rv[i] * rv[i];
  }
  ss2 = block_sum(ss2, sbuf);
  float inv2 = rsqrtf(ss2 * (1.0f / H_DIM) + 1e-6f);
  #pragma unroll
  for (int i = 0; i < 9; ++i) {
    int c = tid + i * 256;
    x2[(long)row * H_DIM + c] = f2bf(rv[i] * inv2 * (1.f + w_pre[c]));
  }
}

__global__ void rms_final_kernel(const float* __restrict__ x, const float* __restrict__ w,
                                 float* __restrict__ out) {
  __shared__ float sbuf[4];
  int row = blockIdx.x, tid = threadIdx.x;
  const float* xr = x + (long)row * H_DIM;
  float v[9]; float ss = 0.f;
  #pragma unroll
  for (int i = 0; i < 9; ++i) { v[i] = xr[tid + i * 256]; ss += v[i] * v[i]; }
  ss = block_sum(ss, sbuf);
  float inv = rsqrtf(ss * (1.0f / H_DIM) + 1e-6f);
  #pragma unroll
  for (int i = 0; i < 9; ++i)
    out[(long)row * H_DIM + tid + i * 256] = v[i] * inv * (1.f + w[tid + i * 256]);
}

// ---------------- RoPE: qkv fp32 -> Qr/Kr bf16 --------------------------------
__global__ void rope_kernel(const float* __restrict__ qkv, const int* __restrict__ positions,
                            __bf16* __restrict__ Qr, __bf16* __restrict__ Kr) {
  int row = blockIdx.x, tid = threadIdx.x;
  float pos = (float)positions[row];
  const float* src = qkv + (long)row * QKV_N;
  const float LOG_TH_128 = 9.210340371976184f / 128.f;  // ln(10000)/128
  #pragma unroll
  for (int l = 0; l < 4; ++l) {            // 1024 q pairs
    int p = tid + l * 256;
    int hh = p >> 7, d = p & 127;
    float fr = pos * expf(-(float)d * LOG_TH_128);
    float sn, cs; sincosf(fr, &sn, &cs);
    float x1 = src[hh * 256 + d], x2 = src[hh * 256 + d + 128];
    Qr[(long)row * QH + hh * 256 + d]       = f2bf(x1 * cs - x2 * sn);
    Qr[(long)row * QH + hh * 256 + d + 128] = f2bf(x2 * cs + x1 * sn);
  }
  #pragma unroll
  for (int l = 0; l < 2; ++l) {            // 512 k pairs
    int p = tid + l * 256;
    int hh = p >> 7, d = p & 127;
    float fr = pos * expf(-(float)d * LOG_TH_128);
    float sn, cs; sincosf(fr, &sn, &cs);
    float x1 = src[QH + hh * 256 + d], x2 = src[QH + hh * 256 + d + 128];
    Kr[(long)row * KVH + hh * 256 + d]       = f2bf(x1 * cs - x2 * sn);
    Kr[(long)row * KVH + hh * 256 + d + 128] = f2bf(x2 * cs + x1 * sn);
  }
}

// ---------------- GEMM: C[M][N] = A[M][K](bf16) x B[N][K](bf16) ---------------
// 128x128 tile, 4 waves 2x2, BK=64 (32 MFMA per barrier pair), global_load_lds
// width 16, XOR chunk swizzle (source-permuted; LDS dest stays lane-contiguous).
// Used for the small GEMMs (Wo, down) where 256^2 tiles would under-occupy.
template <int EPI>
__global__ void gemm_bt(const __bf16* __restrict__ A, const __bf16* __restrict__ B,
                        void* __restrict__ Cout, int K, int ldc) {
  __shared__ __bf16 As[128 * 64];
  __shared__ __bf16 Bs[128 * 64];
  int tid = threadIdx.x;
  int wave = tid >> 6, lane = tid & 63;
  int wm = wave >> 1, wn = wave & 1;
  int q4 = lane >> 4, l15 = lane & 15;
  long bm = (long)blockIdx.y * 128, bn = (long)blockIdx.x * 128;

  int r8 = tid >> 3;                         // 0..31
  int cs = (tid & 7) ^ (r8 & 7);
  const __bf16* Ag = A + (bm + r8) * K + cs * 8;
  const __bf16* Bg = B + (bn + r8) * K + cs * 8;
  __bf16* Asd = As + tid * 8;
  __bf16* Bsd = Bs + tid * 8;

  int moff[4], noff[4];
  #pragma unroll
  for (int i = 0; i < 4; ++i) {
    moff[i] = (wm * 64 + i * 16 + l15) * 64;
    noff[i] = (wn * 64 + i * 16 + l15) * 64;
  }
  int c0 = (q4 ^ (l15 & 7)) * 8;             // ks=0 element offset; ks=1: ^32
  f32x4 acc[4][4] = {};

  for (int k0 = 0; k0 < K; k0 += 64) {
    #pragma unroll
    for (int l = 0; l < 4; ++l) {
      g2l16(Ag + (long)(l * 32) * K, Asd + l * 2048);
      g2l16(Bg + (long)(l * 32) * K, Bsd + l * 2048);
    }
    Ag += 64; Bg += 64;
    __syncthreads();
    #pragma unroll
    for (int ks = 0; ks < 2; ++ks) {
      int cc = c0 ^ (ks * 32);
      bf16x8 af[4], bfv[4];
      #pragma unroll
      for (int i = 0; i < 4; ++i) af[i]  = *(const bf16x8*)(As + moff[i] + cc);
      #pragma unroll
      for (int j = 0; j < 4; ++j) bfv[j] = *(const bf16x8*)(Bs + noff[j] + cc);
      #pragma unroll
      for (int i = 0; i < 4; ++i)
        #pragma unroll
        for (int j = 0; j < 4; ++j)
          acc[i][j] = __builtin_amdgcn_mfma_f32_16x16x32_bf16(af[i], bfv[j], acc[i][j], 0, 0, 0);
    }
    __syncthreads();
  }

  if (EPI == 0) {
    float* C = (float*)Cout;
    #pragma unroll
    for (int i = 0; i < 4; ++i)
      #pragma unroll
      for (int r = 0; r < 4; ++r) {
        long m = bm + wm * 64 + i * 16 + q4 * 4 + r;
        #pragma unroll
        for (int j = 0; j < 4; ++j)
          C[m * ldc + bn + wn * 64 + j * 16 + l15] = acc[i][j][r];
      }
  } else {
    __bf16* C = (__bf16*)Cout;
    #pragma unroll
    for (int i = 0; i < 4; ++i)
      #pragma unroll
      for (int r = 0; r < 4; ++r) {
        long m = bm + wm * 64 + i * 16 + q4 * 4 + r;
        #pragma unroll
        for (int jj = 0; jj < 2; ++jj) {
          float gt = acc[i][2 * jj][r];
          float up = acc[i][2 * jj + 1][r];
          float u = 0.7978845608f * (gt + 0.044715f * gt * gt * gt);
          float e = __builtin_amdgcn_exp2f(u * 2.8853900817779268f);
          float gl = gt * (1.0f - __builtin_amdgcn_rcpf(e + 1.0f));
          long a = (bn >> 1) + wn * 32 + jj * 16 + l15;
          C[m * ldc + a] = f2bf(gl * up);
        }
      }
  }
}

// ---------------- GEMM: 256x256 8-phase schedule (T2+T3+T4+T5) ----------------
// 8 waves (2M x 4N), 512 threads, BK=64, 128 KiB LDS double-buffer.
// Per iteration: 2 K-tiles, 8 phases.  Phase = (buffer, mh, ks) quadrant:
//   ph1(5): load ALL 8 B-frags of the tile into regs + 4 A-frags (mh0,ks0)
//           -> B LDS region free after ph1(5); A half h free after its 2 phases.
//   each phase stages exactly one half-tile (2 x global_load_lds_dwordx4) into
//   a region freed >=1 phase ago; vmcnt(6) ONLY at phases 4 and 8 guarantees
//   the next buffer's tile has fully landed while 3 half-tiles stay in flight.
// Requires K % 128 == 0 and K/64 >= 4.
template <int EPI>
__global__ __launch_bounds__(512, 2)
void gemm8(const __bf16* __restrict__ A, const __bf16* __restrict__ B,
           void* __restrict__ Cout, int K, int ldc) {
  __shared__ __bf16 As[2][16384];   // [buf][256 rows x 64 k], chunk slot = c ^ (row&7)
  __shared__ __bf16 Bs[2][16384];
  const __bf16* Asb = (const __bf16*)As;
  const __bf16* Bsb = (const __bf16*)Bs;

  int tid = threadIdx.x;            // 0..511
  int wave = tid >> 6, lane = tid & 63;
  int wm = wave >> 2;               // 0..1
  int wn = wave & 3;                // 0..3
  int q4 = lane >> 4, l15 = lane & 15;
  int xk = l15 & 7;

  // bijective XCD swizzle (nwg = 256 / 1152 here, both % 8 == 0)
  int nwgx = gridDim.x;
  int nwg = nwgx * gridDim.y;
  int orig = blockIdx.y * nwgx + blockIdx.x;
  int qd = nwg >> 3, rm = nwg & 7;
  int xcd = orig & 7, idx = orig >> 3;
  int swz = (xcd < rm ? xcd * (qd + 1) : rm * (qd + 1) + (xcd - rm) * qd) + idx;
  long bm = (long)(swz / nwgx) * 256;
  long bn = (long)(swz % nwgx) * 256;

  // staging: one g2l16 call covers 64 rows (512 lanes x 16B); thread handles
  // row tid>>3, chunk slot tid&7, global chunk (tid&7)^(row&7) (inverse swizzle).
  int rr = tid >> 3;                 // 0..63
  int cs = (tid & 7) ^ (rr & 7);
  const __bf16* Ag = A + (bm + rr) * (long)K + cs * 8;
  const __bf16* Bg = B + (bn + rr) * (long)K + cs * 8;
  __bf16* Asd = (__bf16*)As + tid * 8;
  __bf16* Bsd = (__bf16*)Bs + tid * 8;

#define ST_A(buf, h, kof) do { \
    g2l16(Ag + ((h) * 128LL      ) * K + (kof), Asd + (buf) * 16384 + (h) * 8192); \
    g2l16(Ag + ((h) * 128LL + 64 ) * K + (kof), Asd + (buf) * 16384 + (h) * 8192 + 4096); } while (0)
#define ST_B(buf, h, kof) do { \
    g2l16(Bg + ((h) * 128LL      ) * K + (kof), Bsd + (buf) * 16384 + (h) * 8192); \
    g2l16(Bg + ((h) * 128LL + 64 ) * K + (kof), Bsd + (buf) * 16384 + (h) * 8192 + 4096); } while (0)

  // fragment offsets: A row = mh*128 + wm*64 + f*16 + l15 ; B row = wn*64 + j*16 + l15
  int aOff[4], bOff[4];
  #pragma unroll
  for (int i = 0; i < 4; ++i) {
    aOff[i] = (wm * 64 + i * 16 + l15) * 64;
    bOff[i] = (wn * 64 + i * 16 + l15) * 64;
  }

#define PH_LOAD_A(buf, mh, ks) \
  { _Pragma("unroll") for (int f = 0; f < 4; ++f) \
      afr[f] = *(const bf16x8*)(Asb + (buf) * 16384 + (mh) * 8192 + aOff[f] + ((((ks) * 4 + q4) ^ xk) * 8)); }
#define PH_LOAD_B(buf) \
  { _Pragma("unroll") for (int ks2 = 0; ks2 < 2; ++ks2) \
    _Pragma("unroll") for (int j = 0; j < 4; ++j) \
      bfr[ks2][j] = *(const bf16x8*)(Bsb + (buf) * 16384 + bOff[j] + (((ks2 * 4 + q4) ^ xk) * 8)); }
#define PH_CORE(mh, ks) \
  __builtin_amdgcn_s_barrier(); \
  asm volatile("s_waitcnt lgkmcnt(0)" ::: "memory"); \
  __builtin_amdgcn_s_setprio(1); \
  { _Pragma("unroll") for (int f = 0; f < 4; ++f) \
    _Pragma("unroll") for (int j = 0; j < 4; ++j) \
      acc[(mh) * 4 + f][j] = __builtin_amdgcn_mfma_f32_16x16x32_bf16(afr[f], bfr[ks][j], acc[(mh) * 4 + f][j], 0, 0, 0); } \
  __builtin_amdgcn_s_setprio(0)
#define BAR   __builtin_amdgcn_s_barrier()
#define WVM6  asm volatile("s_waitcnt vmcnt(6)" ::: "memory")
#define WVM0  asm volatile("s_waitcnt vmcnt(0)" ::: "memory")

  f32x4 acc[8][4] = {};
  bf16x8 bfr[2][4];
  bf16x8 afr[4];

  int nt = K >> 6;                   // K-tiles (even, >= 4)
  int nit = (nt >> 1) - 1;           // main-loop iterations (pairs of tiles)

  // prologue: tile 0 fully, tile 1 all but A-h1  (7 half-tiles = 14 loads)
  ST_B(0, 0, 0); ST_B(0, 1, 0); ST_A(0, 0, 0); ST_A(0, 1, 0);
  ST_B(1, 0, 64); ST_B(1, 1, 64); ST_A(1, 0, 64);
  WVM6;                              // oldest 8 loads (tile 0) landed
  BAR;

  for (int it = 0; it < nit; ++it) {
    const long k0 = (long)it * 128;  // k offset of tile T=2it (buf0); T+1 in buf1
    // ph1: (buf0, mh0, ks0); stage (T+1).A-h1 -> buf1
    PH_LOAD_B(0); PH_LOAD_A(0, 0, 0); ST_A(1, 1, k0 + 64);
    asm volatile("s_waitcnt lgkmcnt(8)" ::: "memory");
    PH_CORE(0, 0); BAR;
    // ph2: stage (T+2).B-h0 -> buf0 (B freed after ph1)
    PH_LOAD_A(0, 0, 1); ST_B(0, 0, k0 + 128);
    PH_CORE(0, 1); BAR;
    // ph3: stage (T+2).B-h1
    PH_LOAD_A(0, 1, 0); ST_B(0, 1, k0 + 128);
    PH_CORE(1, 0); BAR;
    // ph4: stage (T+2).A-h0 (freed after ph2); vmcnt(6) -> tile T+1 complete
    PH_LOAD_A(0, 1, 1); ST_A(0, 0, k0 + 128);
    PH_CORE(1, 1); WVM6; BAR;
    // ph5: (buf1, mh0, ks0); stage (T+2).A-h1 (freed after ph4)
    PH_LOAD_B(1); PH_LOAD_A(1, 0, 0); ST_A(0, 1, k0 + 128);
    asm volatile("s_waitcnt lgkmcnt(8)" ::: "memory");
    PH_CORE(0, 0); BAR;
    // ph6: stage (T+3).B-h0 -> buf1 (B freed after ph5)
    PH_LOAD_A(1, 0, 1); ST_B(1, 0, k0 + 192);
    PH_CORE(0, 1); BAR;
    // ph7: stage (T+3).B-h1
    PH_LOAD_A(1, 1, 0); ST_B(1, 1, k0 + 192);
    PH_CORE(1, 0); BAR;
    // ph8: stage (T+3).A-h0; vmcnt(6) -> tile T+2 complete
    PH_LOAD_A(1, 1, 1); ST_A(1, 0, k0 + 192);
    PH_CORE(1, 1); WVM6; BAR;
  }

  // epilogue iteration: tiles nt-2 (buf0), nt-1 (buf1); only stage left is
  // (nt-1).A-h1 at ph1; full drain at ph4.
  {
    const long k0 = (long)(nt - 2) * 64;
    PH_LOAD_B(0); PH_LOAD_A(0, 0, 0); ST_A(1, 1, k0 + 64);
    asm volatile("s_waitcnt lgkmcnt(8)" ::: "memory");
    PH_CORE(0, 0); BAR;
    PH_LOAD_A(0, 0, 1); PH_CORE(0, 1); BAR;
    PH_LOAD_A(0, 1, 0); PH_CORE(1, 0); BAR;
    PH_LOAD_A(0, 1, 1); PH_CORE(1, 1); WVM0; BAR;
    PH_LOAD_B(1); PH_LOAD_A(1, 0, 0); PH_CORE(0, 0); BAR;
    PH_LOAD_A(1, 0, 1); PH_CORE(0, 1); BAR;
    PH_LOAD_A(1, 1, 0); PH_CORE(1, 0); BAR;
    PH_LOAD_A(1, 1, 1); PH_CORE(1, 1);
  }

#undef ST_A
#undef ST_B
#undef PH_LOAD_A
#undef PH_LOAD_B
#undef PH_CORE
#undef BAR
#undef WVM6
#undef WVM0

  if (EPI == 0) {
    float* C = (float*)Cout;
    #pragma unroll
    for (int mi = 0; mi < 8; ++mi) {
      int mh = mi >> 2, f = mi & 3;
      #pragma unroll
      for (int r = 0; r < 4; ++r) {
        long m = bm + mh * 128 + wm * 64 + f * 16 + q4 * 4 + r;
        #pragma unroll
        for (int j = 0; j < 4; ++j)
          C[m * ldc + bn + wn * 64 + j * 16 + l15] = acc[mi][j][r];
      }
    }
  } else {
    __bf16* C = (__bf16*)Cout;
    #pragma unroll
    for (int mi = 0; mi < 8; ++mi) {
      int mh = mi >> 2, f = mi & 3;
      #pragma unroll
      for (int r = 0; r < 4; ++r) {
        long m = bm + mh * 128 + wm * 64 + f * 16 + q4 * 4 + r;
        #pragma unroll
        for (int jj = 0; jj < 2; ++jj) {
          float gt = acc[mi][2 * jj][r];
          float up = acc[mi][2 * jj + 1][r];
          float u = 0.7978845608f * (gt + 0.044715f * gt * gt * gt);
          float e = __builtin_amdgcn_exp2f(u * 2.8853900817779268f);
          float gl = gt * (1.0f - __builtin_amdgcn_rcpf(e + 1.0f));
          // gu_map inverse for 256-wide tiles: t=(bn>>7)+(wn>>1), w=wn&1
          long a = (bn >> 1) + (wn >> 1) * 64 + (wn & 1) * 32 + jj * 16 + l15;
          C[m * ldc + a] = f2bf(gl * up);
        }
      }
    }
  }
}

// ---------------- flash attention, sliding window 1024, softcap 50 ------------
// Fixed-max softmax: softcap bounds s to (-50,50) so p=exp(s) stays in range.
// No running max, no rescale; l reduced once at the end. 64-key tiles.
__global__ void attn_kernel(const __bf16* __restrict__ Qr, const __bf16* __restrict__ Kr,
                            const __bf16* __restrict__ VT, __bf16* __restrict__ AT) {
  __shared__ __bf16 Kt[64 * 256];   // [key][d], chunk slot = c ^ (key&7)
  __shared__ __bf16 Vt[256 * 64];   // [d][key], chunk slot = c ^ (d&7)
  __shared__ __bf16 Pt[4][16 * 72]; // per-wave P relayout, row stride 72
  int tid = threadIdx.x, wave = tid >> 6, lane = tid & 63;
  int q4 = lane >> 4, l15 = lane & 15;
  int h = blockIdx.y, hk = h >> 1;
  int qb = blockIdx.x * 64;
  int wqb = qb + wave * 16;

  bf16x8 qf[8];
  {
    const __bf16* qp = Qr + (long)(wqb + l15) * QH + h * HDIM + q4 * 8;
    #pragma unroll
    for (int ks = 0; ks < 8; ++ks) qf[ks] = *(const bf16x8*)(qp + ks * 32);
  }
  f32x4 Oa[16] = {};
  float lsum[4] = {0.f, 0.f, 0.f, 0.f};

  int csk = (tid & 31) ^ ((tid >> 5) & 7);
  const __bf16* Kh = Kr + (long)(tid >> 5) * KVH + hk * HDIM + csk * 8;
  int csv = (tid & 7) ^ ((tid >> 3) & 7);
  const __bf16* Vh = VT + (long)(hk * HDIM + (tid >> 3)) * S_LEN + csv * 8;

  int lo = qb - 1023; if (lo < 0) lo = 0;
  int t0 = lo >> 6, t1 = qb >> 6;
  for (int t = t0; t <= t1; ++t) {
    int k0 = t * 64;
    #pragma unroll
    for (int l = 0; l < 8; ++l) {
      g2l16(Kh + ((long)k0 + l * 8) * KVH, Kt + tid * 8 + l * 2048);
      g2l16(Vh + k0 + (long)(l * 32) * S_LEN, Vt + tid * 8 + l * 2048);
    }
    __syncthreads();
    bool active = (k0 <= wqb + 15) && (k0 + 63 >= wqb - 1023);
    if (active) {
      f32x4 Sa[4] = {};
      #pragma unroll
      for (int ks = 0; ks < 8; ++ks)
        #pragma unroll
        for (int j = 0; j < 4; ++j) {
          int key = j * 16 + l15;
          int cc = (ks * 4 + q4) ^ (l15 & 7);       // key&7 == l15&7
          bf16x8 kf = *(const bf16x8*)(Kt + key * 256 + cc * 8);
          Sa[j] = __builtin_amdgcn_mfma_f32_16x16x32_bf16(qf[ks], kf, Sa[j], 0, 0, 0);
        }
      #pragma unroll
      for (int r = 0; r < 4; ++r) {
        int qi = wqb + q4 * 4 + r;
        #pragma unroll
        for (int j = 0; j < 4; ++j) {
          int kj = k0 + j * 16 + l15;
          float y = Sa[j][r] * 1.25e-3f;            // * SCALE(1/16) / 50
          float e = __builtin_amdgcn_exp2f(y * 2.8853900817779268f);
          float p = __builtin_amdgcn_exp2f(72.13475204444817f
                     - 144.26950408889634f * __builtin_amdgcn_rcpf(e + 1.0f));
          bool ok = (kj <= qi) && (qi - kj < 1024);
          p = ok ? p : 0.0f;
          lsum[r] += p;
          Pt[wave][(q4 * 4 + r) * 72 + j * 16 + l15] = f2bf(p);
        }
      }
      asm volatile("s_waitcnt lgkmcnt(0)" ::: "memory");
      bf16x8 pf[2];
      #pragma unroll
      for (int ks = 0; ks < 2; ++ks)
        pf[ks] = *(const bf16x8*)(&Pt[wave][l15 * 72 + ks * 32 + q4 * 8]);
      #pragma unroll
      for (int f = 0; f < 16; ++f) {
        int d = f * 16 + l15;
        #pragma unroll
        for (int ks = 0; ks < 2; ++ks) {
          int cc = (ks * 4 + q4) ^ (l15 & 7);       // d&7 == l15&7
          bf16x8 vf = *(const bf16x8*)(Vt + d * 64 + cc * 8);
          Oa[f] = __builtin_amdgcn_mfma_f32_16x16x32_bf16(pf[ks], vf, Oa[f], 0, 0, 0);
        }
      }
    }
    __syncthreads();
  }
  #pragma unroll
  for (int r = 0; r < 4; ++r) {
    float v = lsum[r];
    #pragma unroll
    for (int o = 1; o < 16; o <<= 1) v += __shfl_xor(v, o);
    lsum[r] = __builtin_amdgcn_rcpf(v);
  }
  #pragma unroll
  for (int f = 0; f < 16; ++f)
    #pragma unroll
    for (int r = 0; r < 4; ++r) {
      long qi = wqb + q4 * 4 + r;
      AT[qi * QH + h * HDIM + f * 16 + l15] = f2bf(Oa[f][r] * lsum[r]);
    }
}

// ---------------- launch ------------------------------------------------------
extern "C" void kernel_launch(void* const* d_in, const int* in_sizes, int n_in,
                              void* d_out, int out_size, void* d_ws, size_t ws_size,
                              hipStream_t stream) {
  (void)in_sizes; (void)n_in; (void)out_size; (void)ws_size;
  const int*   positions = (const int*)d_in[0];
  const float* hidden    = (const float*)d_in[1];
  const float* w_qkv     = (const float*)d_in[2];
  const float* w_o       = (const float*)d_in[3];
  const float* w_gu      = (const float*)d_in[4];
  const float* w_dn      = (const float*)d_in[5];
  const float* w_in_ln   = (const float*)d_in[6];
  const float* w_post    = (const float*)d_in[7];
  const float* w_pre     = (const float*)d_in[8];
  const float* w_pff     = (const float*)d_in[9];
  float* out_h   = (float*)d_out;
  float* out_res = out_h + (size_t)S_LEN * H_DIM;

  char* p = (char*)d_ws;
  auto take = [&](size_t b) { char* r = p; p += (b + 255) & ~(size_t)255; return r; };
  __bf16* Wqkv = (__bf16*)take((size_t)QKV_N * H_DIM * 2);
  __bf16* Wo   = (__bf16*)take((size_t)H_DIM * QH * 2);
  __bf16* Wgu  = (__bf16*)take((size_t)2 * INTER * H_DIM * 2);
  __bf16* Wdn  = (__bf16*)take((size_t)H_DIM * INTER * 2);
  __bf16* Xn   = (__bf16*)take((size_t)S_LEN * H_DIM * 2);
  char*   Rbig = take((size_t)S_LEN * INTER * 2);
  __bf16* Qrb  = (__bf16*)take((size_t)S_LEN * QH * 2);
  __bf16* Krb  = (__bf16*)take((size_t)S_LEN * KVH * 2);
  __bf16* VTb  = (__bf16*)take((size_t)KVH * S_LEN * 2);
  __bf16* ATb  = (__bf16*)take((size_t)S_LEN * QH * 2);
  float*  Pf   = (float*)take((size_t)S_LEN * H_DIM * 4);
  __bf16* X2   = (__bf16*)take((size_t)S_LEN * H_DIM * 2);
  float*  QKV  = (float*)Rbig;
  __bf16* ACT  = (__bf16*)Rbig;
  float*  Mbuf = Pf;

  dim3 blk(256);
  conv_t_kernel<<<dim3(QKV_N / 32, H_DIM / 32), blk, 0, stream>>>(w_qkv, Wqkv, QKV_N, H_DIM);
  conv_t_kernel<<<dim3(H_DIM / 32, QH / 32),    blk, 0, stream>>>(w_o,   Wo,   H_DIM, QH);
  conv_gu_kernel<<<dim3(2 * INTER / 32, H_DIM / 32), blk, 0, stream>>>(w_gu, Wgu);
  conv_t_kernel<<<dim3(H_DIM / 32, INTER / 32), blk, 0, stream>>>(w_dn,  Wdn,  H_DIM, INTER);
  rms_in_kernel<<<S_LEN, blk, 0, stream>>>(hidden, w_in_ln, Xn);
  gemm8<0><<<dim3(QKV_N / 256, S_LEN / 256), dim3(512), 0, stream>>>(Xn, Wqkv, QKV, H_DIM, QKV_N);
  rope_kernel<<<S_LEN, blk, 0, stream>>>(QKV, positions, Qrb, Krb);
  conv_t_kernel<<<dim3(KVH / 32, S_LEN / 32), blk, 0, stream>>>(QKV + QH + KVH, VTb, QKV_N, S_LEN);
  attn_kernel<<<dim3(S_LEN / 64, NQH), blk, 0, stream>>>(Qrb, Krb, VTb, ATb);
  gemm_bt<0><<<dim3(H_DIM / 128, S_LEN / 128), blk, 0, stream>>>(ATb, Wo, Pf, QH, H_DIM);
  rms_post_attn_kernel<<<S_LEN, blk, 0, stream>>>(Pf, hidden, w_post, w_pre, out_res, X2);
  gemm8<1><<<dim3(2 * INTER / 256, S_LEN / 256), dim3(512), 0, stream>>>(X2, Wgu, ACT, H_DIM, INTER);
  gemm_bt<0><<<dim3(H_DIM / 128, S_LEN / 128), blk, 0, stream>>>(ACT, Wdn, Mbuf, INTER, H_DIM);
  rms_final_kernel<<<S_LEN, blk, 0, stream>>>(Mbuf, w_pff, out_h);
}